// Round 7
// baseline (88.751 us; speedup 1.0000x reference)
//
#include <hip/hip_runtime.h>
#include <hip/hip_bf16.h>

// B=64, I=64, O=64, G=4096, X=4, RHO=1
#define BB 64
#define II 64
#define OO 64
#define GG 4096
#define KP 32            // g per phase (K per MFMA pass); LDS row = 32 shorts
#define NCH 8            // g-chunks (split-K) -> grid 64 x 8 = 512 blocks
#define GC (GG / NCH)    // 512 g per block
#define NPH (GC / KP)    // 16 phases (even)

typedef short bf16x8 __attribute__((ext_vector_type(8)));
typedef short bf16x4 __attribute__((ext_vector_type(4)));
typedef float f32x4  __attribute__((ext_vector_type(4)));

static __device__ __forceinline__ short f2bf(float f) {
    __hip_bfloat16 h = __float2bfloat16(f);
    return __builtin_bit_cast(short, h);
}

// Raw barrier with LDS-only drain: ds ops visible across the barrier, global
// prefetch loads deliberately stay in flight (counted vmcnt at consumer).
static __device__ __forceinline__ void lds_barrier() {
    asm volatile("s_waitcnt lgkmcnt(0)" ::: "memory");
    __builtin_amdgcn_s_barrier();
}

// ---------------------------------------------------------------------------
// Main: bf16 MFMA split-K GEMM, software-pipelined.
//   C[b][(o,x)] += sum_g rbf[b,g] * w[o,g,x]   per block (i, ch) over 512 g.
// 16 phases of K=32; double-buffered LDS; ONE lds_barrier per phase.
//
// r7 change: DEPTH-2 PREFETCH. Two register sets preA/preB alternate by
// phase parity (2 phases per loop iteration -> all indexing static, rule
// #20). Phase p consumes loads issued at phase p-2, so each thread keeps
// 4-8 loads (64-128 B) outstanding at ALL times: 64-128 KB/CU in flight >=
// the 64 KB/phase stream -> HBM queue never drains. r6's depth-1 scheme
// (issue at convert-p, consume at convert-p+1) left the HBM pump idle for
// the ~4.4k-cyc serial tail of every ~10.8k-cyc phase (measured 72 us vs
// 42.5 us floor).
//
// WEIGHT STAGING (r6): lane-contiguous loads; load q of thread t fetches
// float4 (row = q*16 + t>>5, col c = t&31) -> 512 B contiguous per 32-lane
// half per instruction. LDS write = 4 ds_write_b16 at column c ^ (x<<3),
// matching the b128 read swizzle (n&3 == x).
// ---------------------------------------------------------------------------
__global__ __launch_bounds__(512, 4)
void kan_main(const float* __restrict__ xg, const float* __restrict__ grd,
              const float* __restrict__ wts, float* __restrict__ dst,
              int atomic_mode)
{
    __shared__ __align__(16) unsigned short Bs[2][256 * KP];  // [n][k] 16KB x2
    __shared__ __align__(16) unsigned short As[2][BB * KP];   // [m][k]  4KB x2

    const int i  = blockIdx.x;
    const int ch = blockIdx.y;
    const int g0 = ch * GC;          // float4 index (1 float4 per g)

    const int t    = threadIdx.x;
    const int lane = t & 63;
    const int wv   = t >> 6;

    // weight staging map (lane-contiguous)
    const int c  = t & 31;           // g-col within phase
    const int r0 = t >> 5;           // row base (0..15); rows r0 + 16q
    const float4* wrow = reinterpret_cast<const float4*>(wts)
                         + (size_t)i * OO * GG + g0 + c;

    // rbf task map
    const int orow = t >> 3;         // b-row
    const int gq   = t & 7;          // 4-g chunk within phase
    const float4* gp = reinterpret_cast<const float4*>(grd) + g0 + gq * 4;
    const float4  xv = reinterpret_cast<const float4*>(xg)[orow * II + i];

    const int lg  = lane >> 4;       // k-quarter: k = lg*8 + e
    const int r16 = lane & 15;

    f32x4 acc[4][2];
    #pragma unroll
    for (int mt = 0; mt < 4; ++mt)
        #pragma unroll
        for (int nt = 0; nt < 2; ++nt) acc[mt][nt] = {0.f, 0.f, 0.f, 0.f};

    // prologue: preA <- phase 0, preB <- phase 1 (issued after preA)
    float4 preA[4], preB[4];
    #pragma unroll
    for (int q = 0; q < 4; ++q)
        preA[q] = wrow[(size_t)(q * 16 + r0) * GG];
    #pragma unroll
    for (int q = 0; q < 4; ++q)
        preB[q] = wrow[(size_t)(q * 16 + r0) * GG + KP];

    for (int pp = 0; pp < NPH; pp += 2) {
        // ================= phase p = pp (even): buffers [0], preA =========
        {
            const int p = pp;
            unsigned short* Bb = Bs[0];
            unsigned short* Ab = As[0];

            float4 gv[4];
            #pragma unroll
            for (int q = 0; q < 4; ++q) gv[q] = gp[p * KP + q];

            #pragma unroll
            for (int q = 0; q < 4; ++q) {
                const int   row = q * 16 + r0;
                const float4 w4 = preA[q];            // counted-vmcnt wait
                if (p + 2 < NPH)
                    preA[q] = wrow[(size_t)row * GG + (p + 2) * KP];
                unsigned short* bp = &Bb[(row * 4) * KP];
                bp[0 * KP + (c     )] = (unsigned short)f2bf(w4.x);
                bp[1 * KP + (c ^  8)] = (unsigned short)f2bf(w4.y);
                bp[2 * KP + (c ^ 16)] = (unsigned short)f2bf(w4.z);
                bp[3 * KP + (c ^ 24)] = (unsigned short)f2bf(w4.w);
            }

            {
                bf16x4 av;
                #pragma unroll
                for (int q = 0; q < 4; ++q) {
                    const float d0 = xv.x - gv[q].x, d1 = xv.y - gv[q].y,
                                d2 = xv.z - gv[q].z, d3 = xv.w - gv[q].w;
                    av[q] = f2bf(__expf(-(d0*d0 + d1*d1 + d2*d2 + d3*d3)));
                }
                *reinterpret_cast<bf16x4*>(
                    &Ab[orow * KP + ((gq * 4) ^ ((orow & 3) << 3))]) = av;
            }

            lds_barrier();   // buf[0] ready; global prefetch NOT drained

            bf16x8 af[4], bb[2];
            #pragma unroll
            for (int mt = 0; mt < 4; ++mt) {
                const int r = mt * 16 + r16;
                af[mt] = *reinterpret_cast<const bf16x8*>(
                    &As[0][r * KP + ((lg * 8) ^ ((r & 3) << 3))]);
            }
            #pragma unroll
            for (int nt = 0; nt < 2; ++nt) {
                const int r = wv * 32 + nt * 16 + r16;
                bb[nt] = *reinterpret_cast<const bf16x8*>(
                    &Bs[0][r * KP + ((lg * 8) ^ ((r & 3) << 3))]);
            }
            #pragma unroll
            for (int mt = 0; mt < 4; ++mt)
                #pragma unroll
                for (int nt = 0; nt < 2; ++nt)
                    acc[mt][nt] = __builtin_amdgcn_mfma_f32_16x16x32_bf16(
                        af[mt], bb[nt], acc[mt][nt], 0, 0, 0);
        }
        // ================= phase p = pp+1 (odd): buffers [1], preB ========
        {
            const int p = pp + 1;
            unsigned short* Bb = Bs[1];
            unsigned short* Ab = As[1];

            float4 gv[4];
            #pragma unroll
            for (int q = 0; q < 4; ++q) gv[q] = gp[p * KP + q];

            #pragma unroll
            for (int q = 0; q < 4; ++q) {
                const int   row = q * 16 + r0;
                const float4 w4 = preB[q];            // counted-vmcnt wait
                if (p + 2 < NPH)
                    preB[q] = wrow[(size_t)row * GG + (p + 2) * KP];
                unsigned short* bp = &Bb[(row * 4) * KP];
                bp[0 * KP + (c     )] = (unsigned short)f2bf(w4.x);
                bp[1 * KP + (c ^  8)] = (unsigned short)f2bf(w4.y);
                bp[2 * KP + (c ^ 16)] = (unsigned short)f2bf(w4.z);
                bp[3 * KP + (c ^ 24)] = (unsigned short)f2bf(w4.w);
            }

            {
                bf16x4 av;
                #pragma unroll
                for (int q = 0; q < 4; ++q) {
                    const float d0 = xv.x - gv[q].x, d1 = xv.y - gv[q].y,
                                d2 = xv.z - gv[q].z, d3 = xv.w - gv[q].w;
                    av[q] = f2bf(__expf(-(d0*d0 + d1*d1 + d2*d2 + d3*d3)));
                }
                *reinterpret_cast<bf16x4*>(
                    &Ab[orow * KP + ((gq * 4) ^ ((orow & 3) << 3))]) = av;
            }

            lds_barrier();   // buf[1] ready

            bf16x8 af[4], bb[2];
            #pragma unroll
            for (int mt = 0; mt < 4; ++mt) {
                const int r = mt * 16 + r16;
                af[mt] = *reinterpret_cast<const bf16x8*>(
                    &As[1][r * KP + ((lg * 8) ^ ((r & 3) << 3))]);
            }
            #pragma unroll
            for (int nt = 0; nt < 2; ++nt) {
                const int r = wv * 32 + nt * 16 + r16;
                bb[nt] = *reinterpret_cast<const bf16x8*>(
                    &Bs[1][r * KP + ((lg * 8) ^ ((r & 3) << 3))]);
            }
            #pragma unroll
            for (int mt = 0; mt < 4; ++mt)
                #pragma unroll
                for (int nt = 0; nt < 2; ++nt)
                    acc[mt][nt] = __builtin_amdgcn_mfma_f32_16x16x32_bf16(
                        af[mt], bb[nt], acc[mt][nt], 0, 0, 0);
        }
    }

    // ---- epilogue: C/D layout col=lane&15, row=(lane>>4)*4+reg ----
    if (!atomic_mode) {
        float* pp = dst + (size_t)(ch * 64 + i) * (BB * OO * 4);
        #pragma unroll
        for (int mt = 0; mt < 4; ++mt)
            #pragma unroll
            for (int nt = 0; nt < 2; ++nt) {
                const int n  = wv * 32 + nt * 16 + (lane & 15);
                const int mb = mt * 16 + ((lane >> 4) << 2);
                #pragma unroll
                for (int r = 0; r < 4; ++r)
                    pp[(mb + r) * 256 + n] = acc[mt][nt][r];
            }
    } else {
        #pragma unroll
        for (int mt = 0; mt < 4; ++mt)
            #pragma unroll
            for (int nt = 0; nt < 2; ++nt) {
                const int n  = wv * 32 + nt * 16 + (lane & 15);
                const int mb = mt * 16 + ((lane >> 4) << 2);
                #pragma unroll
                for (int r = 0; r < 4; ++r)
                    atomicAdd(&dst[(mb + r) * 256 + n], acc[mt][nt][r]);
            }
    }
}

// ---------------------------------------------------------------------------
// Tree-reduce 512 partials -> 4 slices
// ---------------------------------------------------------------------------
__global__ void kan_reduce(const float* __restrict__ part,
                           float* __restrict__ part2, int Q)
{
    const int idx = blockIdx.x * 256 + threadIdx.x;  // [0, 16384)
    const int pg  = blockIdx.y;                      // [0, 4)
    const float* p = part + (size_t)pg * Q * 16384 + idx;
    float s = 0.f;
    #pragma unroll 8
    for (int q = 0; q < Q; ++q) s += p[(size_t)q * 16384];
    part2[pg * 16384 + idx] = s;
}

// ---------------------------------------------------------------------------
// Final sum + SiLU/Cayley (Cl(2,0), static signs) + bias
// ---------------------------------------------------------------------------
__global__ void kan_out(const float* __restrict__ part2,
                        const float* __restrict__ xg,
                        const float* __restrict__ sw,
                        const float* __restrict__ sb,
                        float* __restrict__ out, int R)
{
    const int t = blockIdx.x * 256 + threadIdx.x;    // (b,o)
    const int b = t >> 6, o = t & 63;

    float o0, o1, o2, o3;
    if (R > 0) {
        o0 = o1 = o2 = o3 = 0.f;
        const float4* p2 = reinterpret_cast<const float4*>(part2);
        for (int r = 0; r < R; ++r) {
            const float4 v = p2[(size_t)r * 4096 + t];
            o0 += v.x; o1 += v.y; o2 += v.z; o3 += v.w;
        }
    } else {
        const float4 v = reinterpret_cast<const float4*>(out)[t];
        o0 = v.x; o1 = v.y; o2 = v.z; o3 = v.w;
    }

    const float4* xg4 = reinterpret_cast<const float4*>(xg);
    const float4* sw4 = reinterpret_cast<const float4*>(sw);
    const float4* sb4 = reinterpret_cast<const float4*>(sb);
    #pragma unroll 4
    for (int i = 0; i < II; ++i) {
        const float4 xvv = xg4[b * II + i];
        const float4 swv = sw4[i * OO + o];
        const float4 sbv = sb4[i * OO + o];
        const float s0 = xvv.x / (1.f + __expf(-xvv.x));
        const float s1 = xvv.y / (1.f + __expf(-xvv.y));
        const float s2 = xvv.z / (1.f + __expf(-xvv.z));
        const float s3 = xvv.w / (1.f + __expf(-xvv.w));
        o0 += swv.x * s0 + swv.y * s1 + swv.z * s2 - swv.w * s3 + sbv.x;
        o1 += swv.x * s1 + swv.y * s0 - swv.z * s3 + swv.w * s2 + sbv.y;
        o2 += swv.x * s2 + swv.y * s3 + swv.z * s0 - swv.w * s1 + sbv.z;
        o3 += swv.x * s3 + swv.y * s2 - swv.z * s1 + swv.w * s0 + sbv.w;
    }
    reinterpret_cast<float4*>(out)[t] = make_float4(o0, o1, o2, o3);
}

// ---------------------------------------------------------------------------
extern "C" void kernel_launch(void* const* d_in, const int* in_sizes, int n_in,
                              void* d_out, int out_size, void* d_ws, size_t ws_size,
                              hipStream_t stream)
{
    const float* x   = (const float*)d_in[0];
    const float* grd = (const float*)d_in[1];
    const float* w   = (const float*)d_in[2];
    const float* sw  = (const float*)d_in[3];
    const float* sb  = (const float*)d_in[4];
    float* out = (float*)d_out;
    float* ws  = (float*)d_ws;

    const size_t need = ((size_t)64 * NCH + 4) * 16384 * 4;  // 512 partials + 4 slices

    if (ws_size >= need) {
        float* part2 = ws + (size_t)64 * NCH * 16384;
        kan_main<<<dim3(64, NCH), 512, 0, stream>>>(x, grd, w, ws, 0);
        kan_reduce<<<dim3(64, 4), 256, 0, stream>>>(ws, part2, 64 * NCH / 4);
        kan_out<<<16, 256, 0, stream>>>(part2, x, sw, sb, out, 4);
    } else {
        hipMemsetAsync(d_out, 0, (size_t)out_size * sizeof(float), stream);
        kan_main<<<dim3(64, NCH), 512, 0, stream>>>(x, grd, w, out, 1);
        kan_out<<<16, 256, 0, stream>>>(nullptr, x, sw, sb, out, 0);
    }
}